// Round 2
// baseline (9844.585 us; speedup 1.0000x reference)
//
#include <hip/hip_runtime.h>
#include <math.h>

#define N_PTS 8192
#define M_PTS 2048
#define KLAST 10
#define VARS 3
#define OUTD 32
#define D1 80
#define D2 80
#define TPITCH 68
#define WPITCH 84

typedef float f4 __attribute__((ext_vector_type(4)));

__device__ __forceinline__ float gelu_f(float x) {
    return 0.5f * x * (1.0f + erff(x * 0.70710678118654752f));
}

// Core MLP over a 64-row tile. Caller must have staged activations (36 x 64,
// transposed, pitch TPITCH) into T rows 0..35 and written row metadata before
// calling (core's first barrier covers both). Leaves out[64][33] in T.
// W0 is overlaid into T rows 36..79 (44*68=2992 >= 80*36=2880) and reloaded
// per call; it dies when the layer-1 output overwrites T.
__device__ __forceinline__ void mlp_core(
    float* __restrict__ T, float* __restrict__ W1T, float* __restrict__ W2T,
    const float* __restrict__ W0g, const float* __restrict__ b0g,
    const float* __restrict__ W1g, const float* __restrict__ b1g,
    const float* __restrict__ W2g, const float* __restrict__ b2g,
    int t)
{
    const int tc = t & 15, tr = t >> 4;
    float* W0T = T + 36 * TPITCH;                 // [80 cols][36 k]
    for (int idx = t; idx < D1 * 36; idx += 256) {
        int col = idx / 36, k = idx - col * 36;
        W0T[idx] = W0g[k * D1 + col];             // strided global read, L1-hot
    }
    for (int idx = t; idx < D1 * D2; idx += 256) {
        int k = idx / D2, col = idx - k * D2;
        W1T[col * WPITCH + k] = W1g[idx];
    }
    for (int idx = t; idx < D2 * OUTD; idx += 256) {
        int k = idx / OUTD, col = idx - k * OUTD;
        W2T[col * WPITCH + k] = W2g[idx];
    }
    __syncthreads();

    // ---- layer 1: 36 -> 80, gelu ----
    float acc1[5][4];
#pragma unroll
    for (int c = 0; c < 5; ++c) {
        float b = b0g[tc + 16 * c];
#pragma unroll
        for (int r = 0; r < 4; ++r) acc1[c][r] = b;
    }
#pragma unroll
    for (int kk = 0; kk < 9; ++kk) {
        f4 a[4];
#pragma unroll
        for (int q = 0; q < 4; ++q)
            a[q] = *(const f4*)&T[(4 * kk + q) * TPITCH + 4 * tr];
#pragma unroll
        for (int c = 0; c < 5; ++c) {
            f4 w = *(const f4*)&W0T[(tc + 16 * c) * 36 + 4 * kk];
#pragma unroll
            for (int q = 0; q < 4; ++q) {
#pragma unroll
                for (int r = 0; r < 4; ++r) acc1[c][r] += a[q][r] * w[q];
            }
        }
    }
    __syncthreads();   // all reads of act + W0T done
#pragma unroll
    for (int c = 0; c < 5; ++c) {
        f4 h;
#pragma unroll
        for (int r = 0; r < 4; ++r) h[r] = gelu_f(acc1[c][r]);
        *(f4*)&T[(tc + 16 * c) * TPITCH + 4 * tr] = h;   // H1T
    }
    __syncthreads();

    // ---- layer 2: 80 -> 80, gelu ----
    float acc2[5][4];
#pragma unroll
    for (int c = 0; c < 5; ++c) {
        float b = b1g[tc + 16 * c];
#pragma unroll
        for (int r = 0; r < 4; ++r) acc2[c][r] = b;
    }
#pragma unroll
    for (int kk = 0; kk < 20; ++kk) {
        f4 a[4];
#pragma unroll
        for (int q = 0; q < 4; ++q)
            a[q] = *(const f4*)&T[(4 * kk + q) * TPITCH + 4 * tr];
#pragma unroll
        for (int c = 0; c < 5; ++c) {
            f4 w = *(const f4*)&W1T[(tc + 16 * c) * WPITCH + 4 * kk];
#pragma unroll
            for (int q = 0; q < 4; ++q) {
#pragma unroll
                for (int r = 0; r < 4; ++r) acc2[c][r] += a[q][r] * w[q];
            }
        }
    }
    __syncthreads();
#pragma unroll
    for (int c = 0; c < 5; ++c) {
        f4 h;
#pragma unroll
        for (int r = 0; r < 4; ++r) h[r] = gelu_f(acc2[c][r]);
        *(f4*)&T[(tc + 16 * c) * TPITCH + 4 * tr] = h;   // H2T
    }
    __syncthreads();

    // ---- layer 3: 80 -> 32 ----
    float acc3[2][4];
#pragma unroll
    for (int c = 0; c < 2; ++c) {
        float b = b2g[tc + 16 * c];
#pragma unroll
        for (int r = 0; r < 4; ++r) acc3[c][r] = b;
    }
#pragma unroll
    for (int kk = 0; kk < 20; ++kk) {
        f4 a[4];
#pragma unroll
        for (int q = 0; q < 4; ++q)
            a[q] = *(const f4*)&T[(4 * kk + q) * TPITCH + 4 * tr];
#pragma unroll
        for (int c = 0; c < 2; ++c) {
            f4 w = *(const f4*)&W2T[(tc + 16 * c) * WPITCH + 4 * kk];
#pragma unroll
            for (int q = 0; q < 4; ++q) {
#pragma unroll
                for (int r = 0; r < 4; ++r) acc3[c][r] += a[q][r] * w[q];
            }
        }
    }
    __syncthreads();
#pragma unroll
    for (int c = 0; c < 2; ++c)
#pragma unroll
        for (int r = 0; r < 4; ++r)
            T[(4 * tr + r) * 33 + tc + 16 * c] = acc3[c][r];   // out[e][col]
    __syncthreads();
}

// -------- edge MLP + segment sum (rows = var*E + edge) --------
__global__ __launch_bounds__(256, 2) void agg_kernel(
    const float* __restrict__ grid_in, const float* __restrict__ f0,
    const int* __restrict__ nbr_index, const int* __restrict__ nbr_seg,
    const float* __restrict__ W0g, const float* __restrict__ b0g,
    const float* __restrict__ W1g, const float* __restrict__ b1g,
    const float* __restrict__ W2g, const float* __restrict__ b2g,
    float* __restrict__ f1acc, int E)
{
    __shared__ __attribute__((aligned(16))) float T[D1 * TPITCH];
    __shared__ __attribute__((aligned(16))) float W1T[D1 * WPITCH];
    __shared__ __attribute__((aligned(16))) float W2T[OUTD * WPITCH];
    __shared__ int jb[64], kb[64];
    __shared__ float sxb[64], syb[64];
    const int t = threadIdx.x;
    const int R = 3 * E;
    const int r0 = blockIdx.x * 64;

    if (t < 64) {
        int row = r0 + t, j = 0, key = -1;
        float sx = 0.f, sy = 0.f;
        if (row < R) {
            int v = (row >= 2 * E) ? 2 : ((row >= E) ? 1 : 0);
            int e = row - v * E;
            j = nbr_index[e];
            int s = nbr_seg[e];
            key = (v << 13) + s;
            sx = grid_in[2 * s]; sy = grid_in[2 * s + 1];
        }
        jb[t] = j; kb[t] = key; sxb[t] = sx; syb[t] = sy;
    }
    __syncthreads();
    for (int idx = t; idx < 64 * 9; idx += 256) {
        int e = idx / 9, c = idx - e * 9;
        f4 val = {0.f, 0.f, 0.f, 0.f};
        int key = kb[e];
        if (key >= 0) {
            int j = jb[e];
            if (c == 0) {
                val[0] = grid_in[2 * j]; val[1] = grid_in[2 * j + 1];
                val[2] = sxb[e];         val[3] = syb[e];
            } else {
                int v = key >> 13;
                val = *(const f4*)&f0[(((size_t)v << 13) + j) * OUTD + 4 * (c - 1)];
            }
        }
        T[(4 * c + 0) * TPITCH + e] = val[0];
        T[(4 * c + 1) * TPITCH + e] = val[1];
        T[(4 * c + 2) * TPITCH + e] = val[2];
        T[(4 * c + 3) * TPITCH + e] = val[3];
    }
    mlp_core(T, W1T, W2T, W0g, b0g, W1g, b1g, W2g, b2g, t);
    if (t < OUTD) {
        float run = 0.f; int cur = kb[0];
#pragma unroll 1
        for (int e = 0; e < 64; ++e) {
            int k2 = kb[e];
            if (k2 != cur) {
                if (cur >= 0) atomicAdd(&f1acc[cur * OUTD + t], run);
                run = 0.f; cur = k2;
            }
            run += T[e * 33 + t];
        }
        if (cur >= 0) atomicAdd(&f1acc[cur * OUTD + t], run);
    }
}

// -------- f1 = f1acc * inv_counts + f0 (in place into f1acc) --------
__global__ __launch_bounds__(256) void finalize_kernel(
    float* __restrict__ f1acc, const float* __restrict__ f0,
    const int* __restrict__ counts)
{
    int idx = blockIdx.x * 256 + threadIdx.x;
    int n = (idx >> 5) & (N_PTS - 1);
    int c = counts[n];
    float inv = 1.0f / (float)(c > 1 ? c : 1);
    f1acc[idx] = f1acc[idx] * inv + f0[idx];
}

// -------- kNN interp MLP + mean over K (rows = v*M*K + m*K + kk) --------
__global__ __launch_bounds__(256, 2) void last_kernel(
    const float* __restrict__ grid_in, const float* __restrict__ grid_out,
    const float* __restrict__ f1, const int* __restrict__ nbr_last,
    const float* __restrict__ W0g, const float* __restrict__ b0g,
    const float* __restrict__ W1g, const float* __restrict__ b1g,
    const float* __restrict__ W2g, const float* __restrict__ b2g,
    float* __restrict__ out)
{
    __shared__ __attribute__((aligned(16))) float T[D1 * TPITCH];
    __shared__ __attribute__((aligned(16))) float W1T[D1 * WPITCH];
    __shared__ __attribute__((aligned(16))) float W2T[OUTD * WPITCH];
    __shared__ int jb[64], kb[64];
    __shared__ float sxb[64], syb[64];
    const int t = threadIdx.x;
    const int R = VARS * M_PTS * KLAST;
    const int r0 = blockIdx.x * 64;

    if (t < 64) {
        int row = r0 + t, j = 0, key = -1;
        float sx = 0.f, sy = 0.f;
        if (row < R) {
            int v = row / (M_PTS * KLAST);
            int rem = row - v * (M_PTS * KLAST);
            int m = rem / KLAST;
            j = nbr_last[rem];
            key = (v << 11) + m;
            sx = grid_out[2 * m]; sy = grid_out[2 * m + 1];
        }
        jb[t] = j; kb[t] = key; sxb[t] = sx; syb[t] = sy;
    }
    __syncthreads();
    for (int idx = t; idx < 64 * 9; idx += 256) {
        int e = idx / 9, c = idx - e * 9;
        f4 val = {0.f, 0.f, 0.f, 0.f};
        int key = kb[e];
        if (key >= 0) {
            int j = jb[e];
            if (c == 0) {
                val[0] = grid_in[2 * j]; val[1] = grid_in[2 * j + 1];
                val[2] = sxb[e];         val[3] = syb[e];
            } else {
                int v = key >> 11;
                val = *(const f4*)&f1[(((size_t)v << 13) + j) * OUTD + 4 * (c - 1)];
            }
        }
        T[(4 * c + 0) * TPITCH + e] = val[0];
        T[(4 * c + 1) * TPITCH + e] = val[1];
        T[(4 * c + 2) * TPITCH + e] = val[2];
        T[(4 * c + 3) * TPITCH + e] = val[3];
    }
    mlp_core(T, W1T, W2T, W0g, b0g, W1g, b1g, W2g, b2g, t);
    if (t < OUTD) {
        float run = 0.f; int cur = kb[0];
#pragma unroll 1
        for (int e = 0; e < 64; ++e) {
            int k2 = kb[e];
            if (k2 != cur) {
                if (cur >= 0) {
                    int m = cur & (M_PTS - 1), v = cur >> 11;
                    atomicAdd(&out[(m * VARS + v) * OUTD + t], run * (1.0f / KLAST));
                }
                run = 0.f; cur = k2;
            }
            run += T[e * 33 + t];
        }
        if (cur >= 0) {
            int m = cur & (M_PTS - 1), v = cur >> 11;
            atomicAdd(&out[(m * VARS + v) * OUTD + t], run * (1.0f / KLAST));
        }
    }
}

// -------- projection: rows (n,v) of inp -> f0[(v*N+n)*32+c] --------
__global__ __launch_bounds__(256) void proj_kernel(
    const float* __restrict__ inp,
    const float* __restrict__ W0, const float* __restrict__ b0,
    const float* __restrict__ W1, const float* __restrict__ b1,
    float* __restrict__ f0)
{
    __shared__ float W0s[8 * 64];
    __shared__ float W1s[64 * OUTD];
    __shared__ float xs[32 * 8];
    __shared__ float H[32 * 64];
    const int t = threadIdx.x;
    const int r0 = blockIdx.x * 32;
    for (int idx = t; idx < 512; idx += 256) W0s[idx] = W0[idx];
    for (int idx = t; idx < 64 * OUTD; idx += 256) W1s[idx] = W1[idx];
    xs[t] = inp[r0 * 8 + t];
    __syncthreads();
#pragma unroll
    for (int p = 0; p < 8; ++p) {
        int o = t + 256 * p, r = o >> 6, col = o & 63;
        float s = b0[col];
#pragma unroll
        for (int k = 0; k < 8; ++k) s += xs[r * 8 + k] * W0s[k * 64 + col];
        H[o] = gelu_f(s);
    }
    __syncthreads();
#pragma unroll
    for (int p = 0; p < 4; ++p) {
        int o = t + 256 * p, r = o >> 5, c = o & 31;
        float s = b1[c];
#pragma unroll
        for (int k = 0; k < 64; ++k) s += H[r * 64 + k] * W1s[k * OUTD + c];
        int row = r0 + r;
        int n = row / 3, v = row - n * 3;
        f0[(((size_t)v << 13) + n) * OUTD + c] = s;
    }
}

extern "C" void kernel_launch(void* const* d_in, const int* in_sizes, int n_in,
                              void* d_out, int out_size, void* d_ws, size_t ws_size,
                              hipStream_t stream) {
    const float* inp      = (const float*)d_in[0];
    const float* grid_in  = (const float*)d_in[1];
    const float* grid_out = (const float*)d_in[2];
    const float* pW0 = (const float*)d_in[3];
    const float* pb0 = (const float*)d_in[4];
    const float* pW1 = (const float*)d_in[5];
    const float* pb1 = (const float*)d_in[6];
    const float* i0W0 = (const float*)d_in[7];
    const float* i0b0 = (const float*)d_in[8];
    const float* i0W1 = (const float*)d_in[9];
    const float* i0b1 = (const float*)d_in[10];
    const float* i0W2 = (const float*)d_in[11];
    const float* i0b2 = (const float*)d_in[12];
    const float* i1W0 = (const float*)d_in[13];
    const float* i1b0 = (const float*)d_in[14];
    const float* i1W1 = (const float*)d_in[15];
    const float* i1b1 = (const float*)d_in[16];
    const float* i1W2 = (const float*)d_in[17];
    const float* i1b2 = (const float*)d_in[18];
    const int* nbr_index  = (const int*)d_in[19];
    const int* nbr_seg    = (const int*)d_in[20];
    const int* nbr_counts = (const int*)d_in[21];
    const int* nbr_last   = (const int*)d_in[22];
    const int E = in_sizes[19];

    float* f0    = (float*)d_ws;                         // 3*8192*32
    float* f1acc = f0 + (size_t)VARS * N_PTS * OUTD;     // 3*8192*32

    hipMemsetAsync(f1acc, 0, (size_t)VARS * N_PTS * OUTD * sizeof(float), stream);
    hipMemsetAsync(d_out, 0, (size_t)out_size * sizeof(float), stream);

    proj_kernel<<<(N_PTS * VARS) / 32, 256, 0, stream>>>(inp, pW0, pb0, pW1, pb1, f0);

    int R = 3 * E;
    agg_kernel<<<(R + 63) / 64, 256, 0, stream>>>(grid_in, f0, nbr_index, nbr_seg,
                                                  i0W0, i0b0, i0W1, i0b1, i0W2, i0b2,
                                                  f1acc, E);
    finalize_kernel<<<(VARS * N_PTS * OUTD) / 256, 256, 0, stream>>>(f1acc, f0, nbr_counts);

    int R2 = VARS * M_PTS * KLAST;
    last_kernel<<<(R2 + 63) / 64, 256, 0, stream>>>(grid_in, grid_out, f1acc, nbr_last,
                                                    i1W0, i1b0, i1W1, i1b1, i1W2, i1b2,
                                                    (float*)d_out);
}